// Round 6
// baseline (309.514 us; speedup 1.0000x reference)
//
#include <hip/hip_runtime.h>

#define HDIM 128
#define NGRAPH 64
#define NCLASS 7
#define PG_NODES 384  // nodes per k_pgemm block (6 sub-chunks of 64); 384 halves partials traffic
#define MAXB 2048     // max 64-node buckets: supports n <= 131072

typedef __attribute__((ext_vector_type(8))) __bf16 bf16x8;
typedef __attribute__((ext_vector_type(4))) float f32x4;

__device__ __forceinline__ unsigned short bf16_rne(float f) {
  unsigned u = __float_as_uint(f);
  u += 0x7FFF + ((u >> 16) & 1);
  return (unsigned short)(u >> 16);
}

// ---------------- counting pass: non-returning deg + dual bucket LDS histograms + W2^T bf16 ----------------
// RETURNING fabric atomics ELIMINATED here (was 640k rank=atomicAdd round-trips, ~23.7
// atomics/ns pacing = ~28us). deg is now fire-and-forget; per-edge ranks are assigned
// hierarchically later (bucket reserve in k_edge + LDS counters in k_rank2).

__global__ void k_countw(const int* __restrict__ col, const int* __restrict__ row, int E,
                         int* __restrict__ deg, int* __restrict__ bcntI,
                         int* __restrict__ bcntO, const float* __restrict__ W,
                         unsigned short* __restrict__ wthi, unsigned short* __restrict__ wtlo,
                         int cB, int NB) {
  int b = blockIdx.x;
  if (b < cB) {
    __shared__ int binsI[MAXB], binsO[MAXB];
    int t = threadIdx.x;
    for (int i = t; i < NB; i += 256) { binsI[i] = 0; binsO[i] = 0; }
    __syncthreads();
    int base = b << 11;  // 2048 contiguous edges per block
#pragma unroll
    for (int j = 0; j < 8; j++) {
      int e = base + (j << 8) + t;
      if (e < E) {
        int c = col[e], r = row[e];
        atomicAdd(&deg[c], 1);          // non-returning (result unused)
        atomicAdd(&binsI[c >> 6], 1);
        atomicAdd(&binsO[r >> 6], 1);
      }
    }
    __syncthreads();
    for (int i = t; i < NB; i += 256) {
      int vI = binsI[i]; if (vI) atomicAdd(&bcntI[i], vI);  // non-returning merge
      int vO = binsO[i]; if (vO) atomicAdd(&bcntO[i], vO);
    }
  } else {
    int idx = (b - cB) * 256 + threadIdx.x;  // 0..16383
    int c = idx >> 7, k = idx & 127;
    float v = W[k * 128 + c];
    unsigned short h = bf16_rne(v);
    wthi[idx] = h;
    wtlo[idx] = bf16_rne(v - __uint_as_float((unsigned)h << 16));
  }
}

// exclusive scan of deg (tile-local) -> packed node metadata + self-term inits:
//   od[i] = { off_local | batch[i]<<24 , dinv_bits }
//   dx[i] = { dinv , x }
//   sd[i] = { dinv^2 * x  (s self-init) , dinv }
__global__ void k_scan1(const int* __restrict__ in, int n, const int* __restrict__ batch,
                        const float* __restrict__ x, int2* __restrict__ od,
                        float2* __restrict__ dx, float2* __restrict__ sd,
                        int* __restrict__ tileSums) {
  __shared__ int sh[256];
  int t = threadIdx.x;
  int base = blockIdx.x * 1024 + t * 4;
  int v[4], dg[4], sum = 0;
#pragma unroll
  for (int j = 0; j < 4; j++) {
    int idx = base + j;
    int d = (idx < n) ? in[idx] : 0;
    dg[j] = d;
    v[j] = sum; sum += d;
  }
  sh[t] = sum; __syncthreads();
  for (int o = 1; o < 256; o <<= 1) {
    int val = (t >= o) ? sh[t - o] : 0;
    __syncthreads();
    sh[t] += val;
    __syncthreads();
  }
  int excl = (t == 0) ? 0 : sh[t - 1];
  if (t == 255) tileSums[blockIdx.x] = sh[255];
#pragma unroll
  for (int j = 0; j < 4; j++) {
    int idx = base + j;
    if (idx < n) {
      int g = batch[idx];
      float xv = x[idx];
      float dinv = rsqrtf((float)(dg[j] + 1));  // +1 self-loop
      float dd = dinv * dinv;
      od[idx] = make_int2((excl + v[j]) | (g << 24), __float_as_int(dinv));
      dx[idx] = make_float2(dinv, xv);
      sd[idx] = make_float2(dd * xv, dinv);
    }
  }
}

__global__ void k_scan2(int* __restrict__ tileSums, int numTiles) {
  __shared__ int sh[128];
  int t = threadIdx.x;
  sh[t] = (t < numTiles) ? tileSums[t] : 0;
  __syncthreads();
  for (int o = 1; o < 128; o <<= 1) {
    int val = (t >= o) ? sh[t - o] : 0;
    __syncthreads();
    sh[t] += val;
    __syncthreads();
  }
  if (t < numTiles) tileSums[t] = (t == 0) ? 0 : sh[t - 1];
}

// single-block dual scan: bucket counts (in & out) -> boff (exclusive, +E at [NB]) + cursors
__global__ void k_bscan2(const int* __restrict__ bcntI, int* __restrict__ boffI,
                         int* __restrict__ curI, const int* __restrict__ bcntO,
                         int* __restrict__ boffO, int* __restrict__ curO, int NB, int E) {
  __shared__ int sh[1024];
  int t = threadIdx.x;
  for (int s = 0; s < 2; s++) {
    const int* src = s ? bcntO : bcntI;
    int* boff = s ? boffO : boffI;
    int* cur  = s ? curO  : curI;
    int i0 = 2 * t, i1 = 2 * t + 1;
    int a0 = (i0 < NB) ? src[i0] : 0;
    int a1 = (i1 < NB) ? src[i1] : 0;
    sh[t] = a0 + a1;
    __syncthreads();
    for (int o = 1; o < 1024; o <<= 1) {
      int v = (t >= o) ? sh[t - o] : 0;
      __syncthreads();
      sh[t] += v;
      __syncthreads();
    }
    int ex = (t == 0) ? 0 : sh[t - 1];
    if (i0 < NB) { boff[i0] = ex; cur[i0] = ex; }
    if (i1 < NB) { boff[i1] = ex + a0; cur[i1] = ex + a0; }
    if (t == 0) boff[NB] = E;
    __syncthreads();
  }
}

// ---------------- edge pass (fused dual brank): bucket slots via LDS two-phase, then payload writes ----------------
// Per block: 4096 edges. Phase 1: intra-block bucket ranks (LDS returning atomics, cheap).
// Phase 2: one returning global atomic per nonzero bucket per side (~470k total, low contention).
// Phase 3: per-edge processing: in-bucket payload {src<<6|dstLocal}, out-bucket payload
// {w, srcLocal<<6|g}, layer-1 agg atomic. pos2/rank arrays + separate k_brank dispatch gone.

__global__ void __launch_bounds__(256) k_edge(const int* __restrict__ row,
                                              const int* __restrict__ col, int E,
                                              const int2* __restrict__ od,
                                              const float2* __restrict__ dx,
                                              int* __restrict__ curI, int* __restrict__ curO,
                                              int* __restrict__ inBL, int2* __restrict__ gw2,
                                              float2* __restrict__ sd, int NB) {
  __shared__ int binsI[MAXB], binsO[MAXB];
  int t = threadIdx.x;
  for (int i = t; i < NB; i += 256) { binsI[i] = 0; binsO[i] = 0; }
  __syncthreads();
  int base = blockIdx.x << 12;  // 4096 edges per block
  int iI[16], iO[16];
#pragma unroll
  for (int j = 0; j < 16; j++) {
    int e = base + (j << 8) + t;
    if (e < E) {
      iI[j] = atomicAdd(&binsI[col[e] >> 6], 1);
      iO[j] = atomicAdd(&binsO[row[e] >> 6], 1);
    } else { iI[j] = 0; iO[j] = 0; }
  }
  __syncthreads();
  for (int i = t; i < NB; i += 256) {
    int vI = binsI[i]; binsI[i] = vI ? atomicAdd(&curI[i], vI) : 0;
    int vO = binsO[i]; binsO[i] = vO ? atomicAdd(&curO[i], vO) : 0;
  }
  __syncthreads();
#pragma unroll
  for (int j = 0; j < 16; j++) {
    int e = base + (j << 8) + t;
    if (e >= E) continue;
    int r = row[e], c = col[e];   // L1-hot re-read (32 KB/block)
    int2 oc = od[c];
    float2 dr = dx[r];
    float w = dr.x * __int_as_float(oc.y);
    int g = (int)(((unsigned)oc.x) >> 24);
    inBL[binsI[c >> 6] + iI[j]] = (r << 6) | (c & 63);
    gw2[binsO[r >> 6] + iO[j]] = make_int2(__float_as_int(w), ((r & 63) << 6) | g);
    unsafeAtomicAdd(&sd[c].x, w * dr.y);
  }
}

// ---------------- bucket list -> per-node in-CSR via LDS counters (64 bins, cheap atomics) ----------------
// Writes land in the bucket's contiguous ~410-entry gwi region (L2-friendly).

__global__ void __launch_bounds__(256) k_rank2(const int* __restrict__ inBL,
                                               const int* __restrict__ boffI,
                                               const int2* __restrict__ od,
                                               const int* __restrict__ ts,
                                               int* __restrict__ gwi, int n) {
  __shared__ int off[64], cnt[64];
  int bi = blockIdx.x, t = threadIdx.x;
  if (t < 64) {
    int node = (bi << 6) + t;
    off[t] = (node < n) ? ((od[node].x & 0xFFFFFF) + ts[node >> 10]) : 0;
    cnt[t] = 0;
  }
  __syncthreads();
  int e0 = boffI[bi], e1 = boffI[bi + 1];
  for (int e = e0 + t; e < e1; e += 256) {
    int v = inBL[e];
    int dl = v & 63;
    int k = atomicAdd(&cnt[dl], 1);
    gwi[off[dl] + k] = v >> 6;
  }
}

// ---------------- fused: h1 = relu(s*W1+b1) recomputed per edge + agg2 ----------------
// Lane-parallel edge gather + register broadcast (R4). Output z as bf16 hi/lo.

__global__ void __launch_bounds__(256) k_l2in(const float2* __restrict__ sd,
                                              const int2* __restrict__ od,
                                              const int* __restrict__ ts,
                                              const int* __restrict__ gwi,
                                              const float* __restrict__ W1,
                                              const float* __restrict__ b1,
                                              ushort2* __restrict__ zhi,
                                              ushort2* __restrict__ zlo, int n, int E) {
  int node = blockIdx.x * 4 + (threadIdx.x >> 6);
  if (node >= n) return;
  int l = threadIdx.x & 63;
  float2 w1 = ((const float2*)W1)[l];
  float2 bv = ((const float2*)b1)[l];
  int2 on = od[node];
  float dstd = __int_as_float(on.y);
  float nself = dstd * dstd;
  float sv = sd[node].x;
  float2 acc;
  acc.x = nself * fmaxf(fmaf(sv, w1.x, bv.x), 0.f);
  acc.y = nself * fmaxf(fmaf(sv, w1.y, bv.y), 0.f);
  int e0 = (on.x & 0xFFFFFF) + ts[node >> 10];
  int e1 = (node + 1 < n) ? ((od[node + 1].x & 0xFFFFFF) + ts[(node + 1) >> 10]) : E;

  for (int eb = e0; eb < e1; eb += 64) {
    int m = e1 - eb; if (m > 64) m = 64;
    int ee = eb + l; if (ee >= e1) ee = e1 - 1;      // clamped, coalesced
    float2 q = sd[gwi[ee]];                          // per-lane independent gather
    float u = q.y * dstd;
    int k = 0;
    for (; k + 4 <= m; k += 4) {
      float q0 = __shfl(q.x, k),     u0 = __shfl(u, k);
      float q1 = __shfl(q.x, k + 1), u1 = __shfl(u, k + 1);
      float q2 = __shfl(q.x, k + 2), u2 = __shfl(u, k + 2);
      float q3 = __shfl(q.x, k + 3), u3 = __shfl(u, k + 3);
      acc.x = fmaf(u0, fmaxf(fmaf(q0, w1.x, bv.x), 0.f), acc.x);
      acc.y = fmaf(u0, fmaxf(fmaf(q0, w1.y, bv.y), 0.f), acc.y);
      acc.x = fmaf(u1, fmaxf(fmaf(q1, w1.x, bv.x), 0.f), acc.x);
      acc.y = fmaf(u1, fmaxf(fmaf(q1, w1.y, bv.y), 0.f), acc.y);
      acc.x = fmaf(u2, fmaxf(fmaf(q2, w1.x, bv.x), 0.f), acc.x);
      acc.y = fmaf(u2, fmaxf(fmaf(q2, w1.y, bv.y), 0.f), acc.y);
      acc.x = fmaf(u3, fmaxf(fmaf(q3, w1.x, bv.x), 0.f), acc.x);
      acc.y = fmaf(u3, fmaxf(fmaf(q3, w1.y, bv.y), 0.f), acc.y);
    }
    for (; k < m; k++) {
      float qk = __shfl(q.x, k), uk = __shfl(u, k);
      acc.x = fmaf(uk, fmaxf(fmaf(qk, w1.x, bv.x), 0.f), acc.x);
      acc.y = fmaf(uk, fmaxf(fmaf(qk, w1.y, bv.y), 0.f), acc.y);
    }
  }

  ushort2 h, lo;
  h.x = bf16_rne(acc.x);
  lo.x = bf16_rne(acc.x - __uint_as_float((unsigned)h.x << 16));
  h.y = bf16_rne(acc.y);
  lo.y = bf16_rne(acc.y - __uint_as_float((unsigned)h.y << 16));
  zhi[(size_t)node * 64 + l] = h;
  zlo[(size_t)node * 64 + l] = lo;
}

// ---------------- GEMM via MFMA: (n x 128) @ (128 x 128) + bias + relu ----------------
// 3-term bf16 split: C = Ahi*Bhi + Ahi*Blo + Alo*Bhi (fp32 accum). Fragment-major LDS.

__global__ void __launch_bounds__(256)
k_gemm_mfma(const unsigned short* __restrict__ zhi, const unsigned short* __restrict__ zlo,
            const unsigned short* __restrict__ whi, const unsigned short* __restrict__ wlo,
            const float* __restrict__ bias, float* __restrict__ out, int n) {
  __shared__ uint4 lds[2048];  // Ahi[0,512) Alo[512,1024) Whi[1024,1536) Wlo[1536,2048) = 32 KB
  const int t = threadIdx.x;
  const int l = t & 63, wv = t >> 6;
  const int wr = wv >> 1, wc = wv & 1;  // wave tile: 64x64 in a 2x2 wave grid
  const int lr = l & 15, lk = l >> 4;
  const int rowBase = blockIdx.x << 7;

  f32x4 acc[4][4];
#pragma unroll
  for (int mt = 0; mt < 4; mt++)
#pragma unroll
    for (int nt = 0; nt < 4; nt++) acc[mt][nt] = (f32x4){0.f, 0.f, 0.f, 0.f};

  for (int ch = 0; ch < 4; ch++) {  // K chunks of 32
    __syncthreads();
#pragma unroll
    for (int i = 0; i < 2; i++) {  // stage A (hi+lo), frag-major
      int s = t + (i << 8);        // 0..511
      int sl = s & 63, rt = s >> 6;
      int row = rowBase + (rt << 4) + (sl & 15);
      int kk = (ch << 5) + ((sl >> 4) << 3);
      uint4 vh = make_uint4(0u, 0u, 0u, 0u), vl = vh;
      if (row < n) {
        vh = *(const uint4*)&zhi[(size_t)row * 128 + kk];
        vl = *(const uint4*)&zlo[(size_t)row * 128 + kk];
      }
      lds[s] = vh;
      lds[512 + s] = vl;
    }
#pragma unroll
    for (int i = 0; i < 2; i++) {  // stage W (hi+lo), frag-major
      int s = t + (i << 8);
      int sl = s & 63, ct = s >> 6;
      int col = (ct << 4) + (sl & 15);
      int kk = (ch << 5) + ((sl >> 4) << 3);
      lds[1024 + s] = *(const uint4*)&whi[col * 128 + kk];
      lds[1536 + s] = *(const uint4*)&wlo[col * 128 + kk];
    }
    __syncthreads();

    bf16x8 ah[4], al[4], bh[4], bl[4];
#pragma unroll
    for (int mt = 0; mt < 4; mt++) {
      int slot = ((wr << 2) + mt) * 64 + l;
      ah[mt] = *(const bf16x8*)&lds[slot];
      al[mt] = *(const bf16x8*)&lds[512 + slot];
    }
#pragma unroll
    for (int nt = 0; nt < 4; nt++) {
      int slot = ((wc << 2) + nt) * 64 + l;
      bh[nt] = *(const bf16x8*)&lds[1024 + slot];
      bl[nt] = *(const bf16x8*)&lds[1536 + slot];
    }
#pragma unroll
    for (int mt = 0; mt < 4; mt++)
#pragma unroll
      for (int nt = 0; nt < 4; nt++) {
        acc[mt][nt] = __builtin_amdgcn_mfma_f32_16x16x32_bf16(ah[mt], bh[nt], acc[mt][nt], 0, 0, 0);
        acc[mt][nt] = __builtin_amdgcn_mfma_f32_16x16x32_bf16(ah[mt], bl[nt], acc[mt][nt], 0, 0, 0);
        acc[mt][nt] = __builtin_amdgcn_mfma_f32_16x16x32_bf16(al[mt], bh[nt], acc[mt][nt], 0, 0, 0);
      }
  }

  // epilogue: C/D layout col = lane&15, row = (lane>>4)*4 + reg  [m89/m91]
  float bv[4];
#pragma unroll
  for (int nt = 0; nt < 4; nt++) bv[nt] = bias[(wc << 6) + (nt << 4) + lr];
#pragma unroll
  for (int mt = 0; mt < 4; mt++) {
    int rbase = rowBase + (wr << 6) + (mt << 4) + (lk << 2);
#pragma unroll
    for (int j = 0; j < 4; j++) {
      int row = rbase + j;
      if (row < n) {
#pragma unroll
        for (int nt = 0; nt < 4; nt++) {
          int c2 = (wc << 6) + (nt << 4) + lr;
          out[(size_t)row * 128 + c2] = fmaxf(acc[mt][nt][j] + bv[nt], 0.f);
        }
      }
    }
  }
}

// ---------------- layer 3 + pool: partials[b] = P_b^T * H_b, P-tile built in LDS from bucket-CSR ----------------

__global__ void __launch_bounds__(256) k_pgemm(const float* __restrict__ H,
                                               const int2* __restrict__ gw2,
                                               const int* __restrict__ boff,
                                               const int2* __restrict__ od,
                                               float* __restrict__ partials, int n) {
  __shared__ float4 Hl4[64 * 32];  // 32 KB  [i][j-quad]
  __shared__ float4 Pl4[64 * 16];  // 16 KB  viewed as float[64][64]
  float* Pl = (float*)Pl4;
  const int t = threadIdx.x;
  const int jl = t & 31;
  const int gq = (t >> 5) << 1;
  float4 acc[8];
#pragma unroll
  for (int i = 0; i < 8; i++) acc[i] = make_float4(0.f, 0.f, 0.f, 0.f);
  const int base0 = blockIdx.x * PG_NODES;

  for (int sub = 0; sub < PG_NODES / 64; sub++) {
    const int base = base0 + sub * 64;
    __syncthreads();
    for (int l = t; l < 2048; l += 256) {
      int i = l >> 5, q = l & 31;
      int node = base + i;
      Hl4[l] = (node < n) ? *(const float4*)&H[(size_t)node * 128 + (q << 2)]
                          : make_float4(0.f, 0.f, 0.f, 0.f);
    }
    for (int l = t; l < 1024; l += 256) Pl4[l] = make_float4(0.f, 0.f, 0.f, 0.f);
    __syncthreads();
    // self term: P[i][batch[i]] += dinv^2
    if (t < 64) {
      int node = base + t;
      if (node < n) {
        int2 o2 = od[node];
        float dv = __int_as_float(o2.y);
        atomicAdd(&Pl[(t << 6) + (int)(((unsigned)o2.x) >> 24)], dv * dv);
      }
    }
    // edge terms from bucket-CSR slice; payload y IS the LDS index (rlocal<<6)|g
    int e0 = 0, e1 = 0;
    if (base < n) {
      int bi = base >> 6;
      e0 = boff[bi];
      e1 = boff[bi + 1];
    }
    for (int e = e0 + t; e < e1; e += 256) {
      int2 p = gw2[e];
      atomicAdd(&Pl[p.y], __int_as_float(p.x));
    }
    __syncthreads();

#define FMA4(A, PV) \
  A.x = fmaf(PV, hv.x, A.x); A.y = fmaf(PV, hv.y, A.y); \
  A.z = fmaf(PV, hv.z, A.z); A.w = fmaf(PV, hv.w, A.w);
#pragma unroll 4
    for (int i = 0; i < 64; i++) {
      float4 hv = Hl4[i * 32 + jl];
      float4 pa = Pl4[i * 16 + gq];
      float4 pb = Pl4[i * 16 + gq + 1];
      FMA4(acc[0], pa.x) FMA4(acc[1], pa.y) FMA4(acc[2], pa.z) FMA4(acc[3], pa.w)
      FMA4(acc[4], pb.x) FMA4(acc[5], pb.y) FMA4(acc[6], pb.z) FMA4(acc[7], pb.w)
    }
#undef FMA4
  }

  float* dst = &partials[(size_t)blockIdx.x * (NGRAPH * HDIM)];
  int gb = (t >> 5) << 3;
#pragma unroll
  for (int gi = 0; gi < 8; gi++)
    *(float4*)&dst[(gb + gi) * HDIM + (jl << 2)] = acc[gi];
}

// parallel partials reduce: grid (32, 8), block 256
__global__ void k_reduce(const float* __restrict__ partials, float* __restrict__ pooled,
                         int nparts) {
  int cell = blockIdx.x * 256 + threadIdx.x;
  int stride = gridDim.y;
  int p = blockIdx.y;
  float a0 = 0.f, a1 = 0.f, a2 = 0.f, a3 = 0.f;
  for (; p + 3 * stride < nparts; p += 4 * stride) {
    a0 += partials[(size_t)p * 8192 + cell];
    a1 += partials[(size_t)(p + stride) * 8192 + cell];
    a2 += partials[(size_t)(p + 2 * stride) * 8192 + cell];
    a3 += partials[(size_t)(p + 3 * stride) * 8192 + cell];
  }
  for (; p < nparts; p += stride) a0 += partials[(size_t)p * 8192 + cell];
  unsafeAtomicAdd(&pooled[cell], (a0 + a1) + (a2 + a3));
}

// fused tail: t1 = pooled/cnt @ W3 + b3 (in LDS), then out = t1 @ Wl + bl
__global__ void k_mid(const float* __restrict__ pooled, const int* __restrict__ batch, int n,
                      const float* __restrict__ W3, const float* __restrict__ b3,
                      const float* __restrict__ Wl, const float* __restrict__ bl,
                      float* __restrict__ out) {
  __shared__ float sh[HDIM];
  __shared__ float invSh;
  int g = blockIdx.x, j = threadIdx.x;
  if (j == 0) {
    int lo = 0, hi = n;
    while (lo < hi) { int m = (lo + hi) >> 1; if (batch[m] < g) lo = m + 1; else hi = m; }
    int a = lo;
    lo = 0; hi = n;
    while (lo < hi) { int m = (lo + hi) >> 1; if (batch[m] < g + 1) lo = m + 1; else hi = m; }
    invSh = 1.f / fmaxf((float)(lo - a), 1.f);
  }
  __syncthreads();
  float inv = invSh;
  float acc = 0.f;
  for (int k = 0; k < HDIM; k++) acc = fmaf(pooled[g * HDIM + k], W3[k * HDIM + j], acc);
  sh[j] = acc * inv + b3[j];
  __syncthreads();
  if (j < NCLASS) {
    float o = bl[j];
    for (int k = 0; k < HDIM; k++) o = fmaf(sh[k], Wl[k * NCLASS + j], o);
    out[g * NCLASS + j] = o;
  }
}

// ---------------- host ----------------

extern "C" void kernel_launch(void* const* d_in, const int* in_sizes, int n_in,
                              void* d_out, int out_size, void* d_ws, size_t ws_size,
                              hipStream_t stream) {
  const float* x   = (const float*)d_in[0];
  const int*   ei  = (const int*)d_in[1];
  const int*   bat = (const int*)d_in[2];
  const float* W1  = (const float*)d_in[3];
  const float* b1  = (const float*)d_in[4];
  const float* W2  = (const float*)d_in[5];
  const float* b2  = (const float*)d_in[6];
  const float* W3  = (const float*)d_in[7];
  const float* b3  = (const float*)d_in[8];
  const float* Wl  = (const float*)d_in[9];
  const float* bl  = (const float*)d_in[10];
  float* out = (float*)d_out;

  const int n = in_sizes[0];
  const int E = in_sizes[1] / 2;
  const int* rowv = ei;            // edge_index[0] : message source
  const int* colv = ei + E;        // edge_index[1] : aggregation destination
  const int NB = (n + 63) >> 6;    // 64-node buckets (<= MAXB for n <= 131072)

  char* w = (char*)d_ws;
  size_t o = 0;
  auto alloc = [&](size_t bytes) {
    size_t r = (o + 255) & ~(size_t)255;
    o = r + bytes;
    return r;
  };
  const int nPB = (n + PG_NODES - 1) / PG_NODES;

  size_t o_deg   = alloc((size_t)n * 4);
  size_t o_pool  = alloc((size_t)NGRAPH * HDIM * 4);
  size_t o_bcntI = alloc((size_t)MAXB * 4);
  size_t o_bcntO = alloc((size_t)MAXB * 4);
  size_t zero_end = o;
  size_t o_ts    = alloc(256 * 4);
  size_t o_boffI = alloc((size_t)(MAXB + 1) * 4);
  size_t o_curI  = alloc((size_t)MAXB * 4);
  size_t o_boffO = alloc((size_t)(MAXB + 1) * 4);
  size_t o_curO  = alloc((size_t)MAXB * 4);
  size_t o_od    = alloc((size_t)n * 8);
  size_t o_dx    = alloc((size_t)n * 8);
  size_t o_sd    = alloc((size_t)n * 8);
  size_t o_wt    = alloc((size_t)HDIM * HDIM * 4);   // wthi (32KB) + wtlo (32KB)
  size_t o_gw    = alloc((size_t)E * 4);             // per-node in-CSR payload (src)
  size_t o_inBL  = alloc((size_t)E * 4);             // in-bucket list {src<<6|dstLocal}
  size_t o_gw2   = alloc((size_t)E * 8);             // out-bucket payload {w, (r&63)<<6|g}
  size_t o_bufA  = alloc((size_t)n * HDIM * 4);      // h2 (gemm out)
  size_t o_bufB  = alloc((size_t)n * HDIM * 4);      // zhi+zlo; partials alias after gemm
  (void)n_in; (void)out_size; (void)ws_size;

  int*    deg      = (int*)(w + o_deg);
  float*  pooled   = (float*)(w + o_pool);
  int*    bcntI    = (int*)(w + o_bcntI);
  int*    bcntO    = (int*)(w + o_bcntO);
  int*    ts       = (int*)(w + o_ts);
  int*    boffI    = (int*)(w + o_boffI);
  int*    curI     = (int*)(w + o_curI);
  int*    boffO    = (int*)(w + o_boffO);
  int*    curO     = (int*)(w + o_curO);
  int2*   od       = (int2*)(w + o_od);
  float2* dx       = (float2*)(w + o_dx);
  float2* sd       = (float2*)(w + o_sd);
  unsigned short* wthi = (unsigned short*)(w + o_wt);
  unsigned short* wtlo = wthi + HDIM * HDIM;
  int*    gwi      = (int*)(w + o_gw);
  int*    inBL     = (int*)(w + o_inBL);
  int2*   gw2      = (int2*)(w + o_gw2);
  float*  bufA     = (float*)(w + o_bufA);
  unsigned short* zhi = (unsigned short*)(w + o_bufB);
  unsigned short* zlo = zhi + (size_t)n * HDIM;
  float*  partials = (float*)(w + o_bufB);           // alias (z dead after gemm)

  hipMemsetAsync(w + o_deg, 0, zero_end - o_deg, stream);

  const int nTiles = (n + 1023) / 1024;
  const int cB = (E + 2047) / 2048;  // 8 contiguous edges per thread
  k_countw<<<cB + 64, 256, 0, stream>>>(colv, rowv, E, deg, bcntI, bcntO, W2,
                                        wthi, wtlo, cB, NB);
  k_scan1<<<nTiles, 256, 0, stream>>>(deg, n, bat, x, od, dx, sd, ts);
  k_scan2<<<1, 128, 0, stream>>>(ts, nTiles);
  k_bscan2<<<1, 1024, 0, stream>>>(bcntI, boffI, curI, bcntO, boffO, curO, NB, E);

  // fused dual-brank + edge processing
  k_edge<<<(E + 4095) / 4096, 256, 0, stream>>>(rowv, colv, E, od, dx, curI, curO,
                                                inBL, gw2, sd, NB);

  // bucket list -> per-node in-CSR
  k_rank2<<<NB, 256, 0, stream>>>(inBL, boffI, od, ts, gwi, n);

  // fused rank-1 h1 + relu + layer-2 aggregation -> z as bf16 hi/lo
  k_l2in<<<(n + 3) / 4, 256, 0, stream>>>(sd, od, ts, gwi, W1, b1,
                                          (ushort2*)zhi, (ushort2*)zlo, n, E);

  // layer 2 GEMM (+bias+relu) on the MFMA pipe: 3-term bf16 split
  k_gemm_mfma<<<(n + 127) / 128, 256, 0, stream>>>(zhi, zlo, wthi, wtlo, b2, bufA, n);

  // layer 3 + pool: P-tile rebuilt in LDS from bucket-CSR; partials then reduced
  k_pgemm<<<nPB, 256, 0, stream>>>(bufA, gw2, boffO, od, partials, n);
  k_reduce<<<dim3(32, 8), 256, 0, stream>>>(partials, pooled, nPB);

  // fused tail: mid GEMM + classifier
  k_mid<<<NGRAPH, HDIM, 0, stream>>>(pooled, bat, n, W3, b3, Wl, bl, out);
}

// Round 7
// 302.979 us; speedup vs baseline: 1.0216x; 1.0216x over previous
//
#include <hip/hip_runtime.h>

#define HDIM 128
#define NGRAPH 64
#define NCLASS 7
#define PG_NODES 128  // grid 782 = 3 blocks/CU, matching the 48KB-LDS occupancy cap.
                      // R5's 384 was a REGRESSION (grid 261 -> 1 block/CU, occ 8.5%, 56.7us):
                      // pgemm is latency-bound; grid TLP beats partials-byte savings.
#define MAXB 2048     // max 64-node buckets: supports n <= 131072

typedef __attribute__((ext_vector_type(8))) __bf16 bf16x8;
typedef __attribute__((ext_vector_type(4))) float f32x4;

__device__ __forceinline__ unsigned short bf16_rne(float f) {
  unsigned u = __float_as_uint(f);
  u += 0x7FFF + ((u >> 16) & 1);
  return (unsigned short)(u >> 16);
}

// ---------------- counting pass: non-returning deg + dual bucket LDS histograms + W2^T bf16 ----------------

__global__ void k_countw(const int* __restrict__ col, const int* __restrict__ row, int E,
                         int* __restrict__ deg, int* __restrict__ bcntI,
                         int* __restrict__ bcntO, const float* __restrict__ W,
                         unsigned short* __restrict__ wthi, unsigned short* __restrict__ wtlo,
                         int cB, int NB) {
  int b = blockIdx.x;
  if (b < cB) {
    __shared__ int binsI[MAXB], binsO[MAXB];
    int t = threadIdx.x;
    for (int i = t; i < NB; i += 256) { binsI[i] = 0; binsO[i] = 0; }
    __syncthreads();
    int base = b << 11;  // 2048 contiguous edges per block
#pragma unroll
    for (int j = 0; j < 8; j++) {
      int e = base + (j << 8) + t;
      if (e < E) {
        int c = col[e], r = row[e];
        atomicAdd(&deg[c], 1);          // non-returning (result unused)
        atomicAdd(&binsI[c >> 6], 1);
        atomicAdd(&binsO[r >> 6], 1);
      }
    }
    __syncthreads();
    for (int i = t; i < NB; i += 256) {
      int vI = binsI[i]; if (vI) atomicAdd(&bcntI[i], vI);  // non-returning merge
      int vO = binsO[i]; if (vO) atomicAdd(&bcntO[i], vO);
    }
  } else {
    int idx = (b - cB) * 256 + threadIdx.x;  // 0..16383
    int c = idx >> 7, k = idx & 127;
    float v = W[k * 128 + c];
    unsigned short h = bf16_rne(v);
    wthi[idx] = h;
    wtlo[idx] = bf16_rne(v - __uint_as_float((unsigned)h << 16));
  }
}

// exclusive scan of deg (tile-local) -> packed node metadata + self-term inits:
//   od[i] = { off_local | batch[i]<<24 , dinv_bits }
//   dx[i] = { dinv , x }
//   sd[i] = { dinv^2 * x  (s self-init) , dinv }
__global__ void k_scan1(const int* __restrict__ in, int n, const int* __restrict__ batch,
                        const float* __restrict__ x, int2* __restrict__ od,
                        float2* __restrict__ dx, float2* __restrict__ sd,
                        int* __restrict__ tileSums) {
  __shared__ int sh[256];
  int t = threadIdx.x;
  int base = blockIdx.x * 1024 + t * 4;
  int v[4], dg[4], sum = 0;
#pragma unroll
  for (int j = 0; j < 4; j++) {
    int idx = base + j;
    int d = (idx < n) ? in[idx] : 0;
    dg[j] = d;
    v[j] = sum; sum += d;
  }
  sh[t] = sum; __syncthreads();
  for (int o = 1; o < 256; o <<= 1) {
    int val = (t >= o) ? sh[t - o] : 0;
    __syncthreads();
    sh[t] += val;
    __syncthreads();
  }
  int excl = (t == 0) ? 0 : sh[t - 1];
  if (t == 255) tileSums[blockIdx.x] = sh[255];
#pragma unroll
  for (int j = 0; j < 4; j++) {
    int idx = base + j;
    if (idx < n) {
      int g = batch[idx];
      float xv = x[idx];
      float dinv = rsqrtf((float)(dg[j] + 1));  // +1 self-loop
      float dd = dinv * dinv;
      od[idx] = make_int2((excl + v[j]) | (g << 24), __float_as_int(dinv));
      dx[idx] = make_float2(dinv, xv);
      sd[idx] = make_float2(dd * xv, dinv);
    }
  }
}

__global__ void k_scan2(int* __restrict__ tileSums, int numTiles) {
  __shared__ int sh[128];
  int t = threadIdx.x;
  sh[t] = (t < numTiles) ? tileSums[t] : 0;
  __syncthreads();
  for (int o = 1; o < 128; o <<= 1) {
    int val = (t >= o) ? sh[t - o] : 0;
    __syncthreads();
    sh[t] += val;
    __syncthreads();
  }
  if (t < numTiles) tileSums[t] = (t == 0) ? 0 : sh[t - 1];
}

// single-block dual scan: bucket counts (in & out) -> boff (exclusive, +E at [NB]) + cursors
__global__ void k_bscan2(const int* __restrict__ bcntI, int* __restrict__ boffI,
                         int* __restrict__ curI, const int* __restrict__ bcntO,
                         int* __restrict__ boffO, int* __restrict__ curO, int NB, int E) {
  __shared__ int sh[1024];
  int t = threadIdx.x;
  for (int s = 0; s < 2; s++) {
    const int* src = s ? bcntO : bcntI;
    int* boff = s ? boffO : boffI;
    int* cur  = s ? curO  : curI;
    int i0 = 2 * t, i1 = 2 * t + 1;
    int a0 = (i0 < NB) ? src[i0] : 0;
    int a1 = (i1 < NB) ? src[i1] : 0;
    sh[t] = a0 + a1;
    __syncthreads();
    for (int o = 1; o < 1024; o <<= 1) {
      int v = (t >= o) ? sh[t - o] : 0;
      __syncthreads();
      sh[t] += v;
      __syncthreads();
    }
    int ex = (t == 0) ? 0 : sh[t - 1];
    if (i0 < NB) { boff[i0] = ex; cur[i0] = ex; }
    if (i1 < NB) { boff[i1] = ex + a0; cur[i1] = ex + a0; }
    if (t == 0) boff[NB] = E;
    __syncthreads();
  }
}

// ---------------- edge pass (fused dual brank): bucket slots via LDS two-phase, then payload writes ----------------

__global__ void __launch_bounds__(256) k_edge(const int* __restrict__ row,
                                              const int* __restrict__ col, int E,
                                              const int2* __restrict__ od,
                                              const float2* __restrict__ dx,
                                              int* __restrict__ curI, int* __restrict__ curO,
                                              int* __restrict__ inBL, int2* __restrict__ gw2,
                                              float2* __restrict__ sd, int NB) {
  __shared__ int binsI[MAXB], binsO[MAXB];
  int t = threadIdx.x;
  for (int i = t; i < NB; i += 256) { binsI[i] = 0; binsO[i] = 0; }
  __syncthreads();
  int base = blockIdx.x << 12;  // 4096 edges per block
  int iI[16], iO[16];
#pragma unroll
  for (int j = 0; j < 16; j++) {
    int e = base + (j << 8) + t;
    if (e < E) {
      iI[j] = atomicAdd(&binsI[col[e] >> 6], 1);
      iO[j] = atomicAdd(&binsO[row[e] >> 6], 1);
    } else { iI[j] = 0; iO[j] = 0; }
  }
  __syncthreads();
  for (int i = t; i < NB; i += 256) {
    int vI = binsI[i]; binsI[i] = vI ? atomicAdd(&curI[i], vI) : 0;
    int vO = binsO[i]; binsO[i] = vO ? atomicAdd(&curO[i], vO) : 0;
  }
  __syncthreads();
#pragma unroll
  for (int j = 0; j < 16; j++) {
    int e = base + (j << 8) + t;
    if (e >= E) continue;
    int r = row[e], c = col[e];   // L1-hot re-read (32 KB/block)
    int2 oc = od[c];
    float2 dr = dx[r];
    float w = dr.x * __int_as_float(oc.y);
    int g = (int)(((unsigned)oc.x) >> 24);
    inBL[binsI[c >> 6] + iI[j]] = (r << 6) | (c & 63);
    gw2[binsO[r >> 6] + iO[j]] = make_int2(__float_as_int(w), ((r & 63) << 6) | g);
    unsafeAtomicAdd(&sd[c].x, w * dr.y);
  }
}

// ---------------- bucket list -> per-node in-CSR via LDS counters (64 bins, cheap atomics) ----------------

__global__ void __launch_bounds__(256) k_rank2(const int* __restrict__ inBL,
                                               const int* __restrict__ boffI,
                                               const int2* __restrict__ od,
                                               const int* __restrict__ ts,
                                               int* __restrict__ gwi, int n) {
  __shared__ int off[64], cnt[64];
  int bi = blockIdx.x, t = threadIdx.x;
  if (t < 64) {
    int node = (bi << 6) + t;
    off[t] = (node < n) ? ((od[node].x & 0xFFFFFF) + ts[node >> 10]) : 0;
    cnt[t] = 0;
  }
  __syncthreads();
  int e0 = boffI[bi], e1 = boffI[bi + 1];
  for (int e = e0 + t; e < e1; e += 256) {
    int v = inBL[e];
    int dl = v & 63;
    int k = atomicAdd(&cnt[dl], 1);
    gwi[off[dl] + k] = v >> 6;
  }
}

// ---------------- fused: h1 = relu(s*W1+b1) recomputed per edge + agg2 ----------------
// Lane-parallel edge gather + register broadcast (R4). Output z as bf16 hi/lo.

__global__ void __launch_bounds__(256) k_l2in(const float2* __restrict__ sd,
                                              const int2* __restrict__ od,
                                              const int* __restrict__ ts,
                                              const int* __restrict__ gwi,
                                              const float* __restrict__ W1,
                                              const float* __restrict__ b1,
                                              ushort2* __restrict__ zhi,
                                              ushort2* __restrict__ zlo, int n, int E) {
  int node = blockIdx.x * 4 + (threadIdx.x >> 6);
  if (node >= n) return;
  int l = threadIdx.x & 63;
  float2 w1 = ((const float2*)W1)[l];
  float2 bv = ((const float2*)b1)[l];
  int2 on = od[node];
  float dstd = __int_as_float(on.y);
  float nself = dstd * dstd;
  float sv = sd[node].x;
  float2 acc;
  acc.x = nself * fmaxf(fmaf(sv, w1.x, bv.x), 0.f);
  acc.y = nself * fmaxf(fmaf(sv, w1.y, bv.y), 0.f);
  int e0 = (on.x & 0xFFFFFF) + ts[node >> 10];
  int e1 = (node + 1 < n) ? ((od[node + 1].x & 0xFFFFFF) + ts[(node + 1) >> 10]) : E;

  for (int eb = e0; eb < e1; eb += 64) {
    int m = e1 - eb; if (m > 64) m = 64;
    int ee = eb + l; if (ee >= e1) ee = e1 - 1;      // clamped, coalesced
    float2 q = sd[gwi[ee]];                          // per-lane independent gather
    float u = q.y * dstd;
    int k = 0;
    for (; k + 4 <= m; k += 4) {
      float q0 = __shfl(q.x, k),     u0 = __shfl(u, k);
      float q1 = __shfl(q.x, k + 1), u1 = __shfl(u, k + 1);
      float q2 = __shfl(q.x, k + 2), u2 = __shfl(u, k + 2);
      float q3 = __shfl(q.x, k + 3), u3 = __shfl(u, k + 3);
      acc.x = fmaf(u0, fmaxf(fmaf(q0, w1.x, bv.x), 0.f), acc.x);
      acc.y = fmaf(u0, fmaxf(fmaf(q0, w1.y, bv.y), 0.f), acc.y);
      acc.x = fmaf(u1, fmaxf(fmaf(q1, w1.x, bv.x), 0.f), acc.x);
      acc.y = fmaf(u1, fmaxf(fmaf(q1, w1.y, bv.y), 0.f), acc.y);
      acc.x = fmaf(u2, fmaxf(fmaf(q2, w1.x, bv.x), 0.f), acc.x);
      acc.y = fmaf(u2, fmaxf(fmaf(q2, w1.y, bv.y), 0.f), acc.y);
      acc.x = fmaf(u3, fmaxf(fmaf(q3, w1.x, bv.x), 0.f), acc.x);
      acc.y = fmaf(u3, fmaxf(fmaf(q3, w1.y, bv.y), 0.f), acc.y);
    }
    for (; k < m; k++) {
      float qk = __shfl(q.x, k), uk = __shfl(u, k);
      acc.x = fmaf(uk, fmaxf(fmaf(qk, w1.x, bv.x), 0.f), acc.x);
      acc.y = fmaf(uk, fmaxf(fmaf(qk, w1.y, bv.y), 0.f), acc.y);
    }
  }

  ushort2 h, lo;
  h.x = bf16_rne(acc.x);
  lo.x = bf16_rne(acc.x - __uint_as_float((unsigned)h.x << 16));
  h.y = bf16_rne(acc.y);
  lo.y = bf16_rne(acc.y - __uint_as_float((unsigned)h.y << 16));
  zhi[(size_t)node * 64 + l] = h;
  zlo[(size_t)node * 64 + l] = lo;
}

// ---------------- GEMM via MFMA: (n x 128) @ (128 x 128) + bias + relu ----------------
// 3-term bf16 split: C = Ahi*Bhi + Ahi*Blo + Alo*Bhi (fp32 accum). Fragment-major LDS.

__global__ void __launch_bounds__(256)
k_gemm_mfma(const unsigned short* __restrict__ zhi, const unsigned short* __restrict__ zlo,
            const unsigned short* __restrict__ whi, const unsigned short* __restrict__ wlo,
            const float* __restrict__ bias, float* __restrict__ out, int n) {
  __shared__ uint4 lds[2048];  // Ahi[0,512) Alo[512,1024) Whi[1024,1536) Wlo[1536,2048) = 32 KB
  const int t = threadIdx.x;
  const int l = t & 63, wv = t >> 6;
  const int wr = wv >> 1, wc = wv & 1;  // wave tile: 64x64 in a 2x2 wave grid
  const int lr = l & 15, lk = l >> 4;
  const int rowBase = blockIdx.x << 7;

  f32x4 acc[4][4];
#pragma unroll
  for (int mt = 0; mt < 4; mt++)
#pragma unroll
    for (int nt = 0; nt < 4; nt++) acc[mt][nt] = (f32x4){0.f, 0.f, 0.f, 0.f};

  for (int ch = 0; ch < 4; ch++) {  // K chunks of 32
    __syncthreads();
#pragma unroll
    for (int i = 0; i < 2; i++) {  // stage A (hi+lo), frag-major
      int s = t + (i << 8);        // 0..511
      int sl = s & 63, rt = s >> 6;
      int row = rowBase + (rt << 4) + (sl & 15);
      int kk = (ch << 5) + ((sl >> 4) << 3);
      uint4 vh = make_uint4(0u, 0u, 0u, 0u), vl = vh;
      if (row < n) {
        vh = *(const uint4*)&zhi[(size_t)row * 128 + kk];
        vl = *(const uint4*)&zlo[(size_t)row * 128 + kk];
      }
      lds[s] = vh;
      lds[512 + s] = vl;
    }
#pragma unroll
    for (int i = 0; i < 2; i++) {  // stage W (hi+lo), frag-major
      int s = t + (i << 8);
      int sl = s & 63, ct = s >> 6;
      int col = (ct << 4) + (sl & 15);
      int kk = (ch << 5) + ((sl >> 4) << 3);
      lds[1024 + s] = *(const uint4*)&whi[col * 128 + kk];
      lds[1536 + s] = *(const uint4*)&wlo[col * 128 + kk];
    }
    __syncthreads();

    bf16x8 ah[4], al[4], bh[4], bl[4];
#pragma unroll
    for (int mt = 0; mt < 4; mt++) {
      int slot = ((wr << 2) + mt) * 64 + l;
      ah[mt] = *(const bf16x8*)&lds[slot];
      al[mt] = *(const bf16x8*)&lds[512 + slot];
    }
#pragma unroll
    for (int nt = 0; nt < 4; nt++) {
      int slot = ((wc << 2) + nt) * 64 + l;
      bh[nt] = *(const bf16x8*)&lds[1024 + slot];
      bl[nt] = *(const bf16x8*)&lds[1536 + slot];
    }
#pragma unroll
    for (int mt = 0; mt < 4; mt++)
#pragma unroll
      for (int nt = 0; nt < 4; nt++) {
        acc[mt][nt] = __builtin_amdgcn_mfma_f32_16x16x32_bf16(ah[mt], bh[nt], acc[mt][nt], 0, 0, 0);
        acc[mt][nt] = __builtin_amdgcn_mfma_f32_16x16x32_bf16(ah[mt], bl[nt], acc[mt][nt], 0, 0, 0);
        acc[mt][nt] = __builtin_amdgcn_mfma_f32_16x16x32_bf16(al[mt], bh[nt], acc[mt][nt], 0, 0, 0);
      }
  }

  // epilogue: C/D layout col = lane&15, row = (lane>>4)*4 + reg  [m89/m91]
  float bv[4];
#pragma unroll
  for (int nt = 0; nt < 4; nt++) bv[nt] = bias[(wc << 6) + (nt << 4) + lr];
#pragma unroll
  for (int mt = 0; mt < 4; mt++) {
    int rbase = rowBase + (wr << 6) + (mt << 4) + (lk << 2);
#pragma unroll
    for (int j = 0; j < 4; j++) {
      int row = rbase + j;
      if (row < n) {
#pragma unroll
        for (int nt = 0; nt < 4; nt++) {
          int c2 = (wc << 6) + (nt << 4) + lr;
          out[(size_t)row * 128 + c2] = fmaxf(acc[mt][nt][j] + bv[nt], 0.f);
        }
      }
    }
  }
}

// ---------------- layer 3 + pool: partials[b] = P_b^T * H_b, P-tile built in LDS from bucket-CSR ----------------

__global__ void __launch_bounds__(256) k_pgemm(const float* __restrict__ H,
                                               const int2* __restrict__ gw2,
                                               const int* __restrict__ boff,
                                               const int2* __restrict__ od,
                                               float* __restrict__ partials, int n) {
  __shared__ float4 Hl4[64 * 32];  // 32 KB  [i][j-quad]
  __shared__ float4 Pl4[64 * 16];  // 16 KB  viewed as float[64][64]
  float* Pl = (float*)Pl4;
  const int t = threadIdx.x;
  const int jl = t & 31;
  const int gq = (t >> 5) << 1;
  float4 acc[8];
#pragma unroll
  for (int i = 0; i < 8; i++) acc[i] = make_float4(0.f, 0.f, 0.f, 0.f);
  const int base0 = blockIdx.x * PG_NODES;

  for (int sub = 0; sub < PG_NODES / 64; sub++) {
    const int base = base0 + sub * 64;
    __syncthreads();
    for (int l = t; l < 2048; l += 256) {
      int i = l >> 5, q = l & 31;
      int node = base + i;
      Hl4[l] = (node < n) ? *(const float4*)&H[(size_t)node * 128 + (q << 2)]
                          : make_float4(0.f, 0.f, 0.f, 0.f);
    }
    for (int l = t; l < 1024; l += 256) Pl4[l] = make_float4(0.f, 0.f, 0.f, 0.f);
    __syncthreads();
    // self term: P[i][batch[i]] += dinv^2
    if (t < 64) {
      int node = base + t;
      if (node < n) {
        int2 o2 = od[node];
        float dv = __int_as_float(o2.y);
        atomicAdd(&Pl[(t << 6) + (int)(((unsigned)o2.x) >> 24)], dv * dv);
      }
    }
    // edge terms from bucket-CSR slice; payload y IS the LDS index (rlocal<<6)|g
    int e0 = 0, e1 = 0;
    if (base < n) {
      int bi = base >> 6;
      e0 = boff[bi];
      e1 = boff[bi + 1];
    }
    for (int e = e0 + t; e < e1; e += 256) {
      int2 p = gw2[e];
      atomicAdd(&Pl[p.y], __int_as_float(p.x));
    }
    __syncthreads();

#define FMA4(A, PV) \
  A.x = fmaf(PV, hv.x, A.x); A.y = fmaf(PV, hv.y, A.y); \
  A.z = fmaf(PV, hv.z, A.z); A.w = fmaf(PV, hv.w, A.w);
#pragma unroll 4
    for (int i = 0; i < 64; i++) {
      float4 hv = Hl4[i * 32 + jl];
      float4 pa = Pl4[i * 16 + gq];
      float4 pb = Pl4[i * 16 + gq + 1];
      FMA4(acc[0], pa.x) FMA4(acc[1], pa.y) FMA4(acc[2], pa.z) FMA4(acc[3], pa.w)
      FMA4(acc[4], pb.x) FMA4(acc[5], pb.y) FMA4(acc[6], pb.z) FMA4(acc[7], pb.w)
    }
#undef FMA4
  }

  float* dst = &partials[(size_t)blockIdx.x * (NGRAPH * HDIM)];
  int gb = (t >> 5) << 3;
#pragma unroll
  for (int gi = 0; gi < 8; gi++)
    *(float4*)&dst[(gb + gi) * HDIM + (jl << 2)] = acc[gi];
}

// parallel partials reduce: grid (32, 8), block 256
__global__ void k_reduce(const float* __restrict__ partials, float* __restrict__ pooled,
                         int nparts) {
  int cell = blockIdx.x * 256 + threadIdx.x;
  int stride = gridDim.y;
  int p = blockIdx.y;
  float a0 = 0.f, a1 = 0.f, a2 = 0.f, a3 = 0.f;
  for (; p + 3 * stride < nparts; p += 4 * stride) {
    a0 += partials[(size_t)p * 8192 + cell];
    a1 += partials[(size_t)(p + stride) * 8192 + cell];
    a2 += partials[(size_t)(p + 2 * stride) * 8192 + cell];
    a3 += partials[(size_t)(p + 3 * stride) * 8192 + cell];
  }
  for (; p < nparts; p += stride) a0 += partials[(size_t)p * 8192 + cell];
  unsafeAtomicAdd(&pooled[cell], (a0 + a1) + (a2 + a3));
}

// fused tail: t1 = pooled/cnt @ W3 + b3 (in LDS), then out = t1 @ Wl + bl
__global__ void k_mid(const float* __restrict__ pooled, const int* __restrict__ batch, int n,
                      const float* __restrict__ W3, const float* __restrict__ b3,
                      const float* __restrict__ Wl, const float* __restrict__ bl,
                      float* __restrict__ out) {
  __shared__ float sh[HDIM];
  __shared__ float invSh;
  int g = blockIdx.x, j = threadIdx.x;
  if (j == 0) {
    int lo = 0, hi = n;
    while (lo < hi) { int m = (lo + hi) >> 1; if (batch[m] < g) lo = m + 1; else hi = m; }
    int a = lo;
    lo = 0; hi = n;
    while (lo < hi) { int m = (lo + hi) >> 1; if (batch[m] < g + 1) lo = m + 1; else hi = m; }
    invSh = 1.f / fmaxf((float)(lo - a), 1.f);
  }
  __syncthreads();
  float inv = invSh;
  float acc = 0.f;
  for (int k = 0; k < HDIM; k++) acc = fmaf(pooled[g * HDIM + k], W3[k * HDIM + j], acc);
  sh[j] = acc * inv + b3[j];
  __syncthreads();
  if (j < NCLASS) {
    float o = bl[j];
    for (int k = 0; k < HDIM; k++) o = fmaf(sh[k], Wl[k * NCLASS + j], o);
    out[g * NCLASS + j] = o;
  }
}

// ---------------- host ----------------

extern "C" void kernel_launch(void* const* d_in, const int* in_sizes, int n_in,
                              void* d_out, int out_size, void* d_ws, size_t ws_size,
                              hipStream_t stream) {
  const float* x   = (const float*)d_in[0];
  const int*   ei  = (const int*)d_in[1];
  const int*   bat = (const int*)d_in[2];
  const float* W1  = (const float*)d_in[3];
  const float* b1  = (const float*)d_in[4];
  const float* W2  = (const float*)d_in[5];
  const float* b2  = (const float*)d_in[6];
  const float* W3  = (const float*)d_in[7];
  const float* b3  = (const float*)d_in[8];
  const float* Wl  = (const float*)d_in[9];
  const float* bl  = (const float*)d_in[10];
  float* out = (float*)d_out;

  const int n = in_sizes[0];
  const int E = in_sizes[1] / 2;
  const int* rowv = ei;            // edge_index[0] : message source
  const int* colv = ei + E;        // edge_index[1] : aggregation destination
  const int NB = (n + 63) >> 6;    // 64-node buckets (<= MAXB for n <= 131072)

  char* w = (char*)d_ws;
  size_t o = 0;
  auto alloc = [&](size_t bytes) {
    size_t r = (o + 255) & ~(size_t)255;
    o = r + bytes;
    return r;
  };
  const int nPB = (n + PG_NODES - 1) / PG_NODES;

  size_t o_deg   = alloc((size_t)n * 4);
  size_t o_pool  = alloc((size_t)NGRAPH * HDIM * 4);
  size_t o_bcntI = alloc((size_t)MAXB * 4);
  size_t o_bcntO = alloc((size_t)MAXB * 4);
  size_t zero_end = o;
  size_t o_ts    = alloc(256 * 4);
  size_t o_boffI = alloc((size_t)(MAXB + 1) * 4);
  size_t o_curI  = alloc((size_t)MAXB * 4);
  size_t o_boffO = alloc((size_t)(MAXB + 1) * 4);
  size_t o_curO  = alloc((size_t)MAXB * 4);
  size_t o_od    = alloc((size_t)n * 8);
  size_t o_dx    = alloc((size_t)n * 8);
  size_t o_sd    = alloc((size_t)n * 8);
  size_t o_wt    = alloc((size_t)HDIM * HDIM * 4);   // wthi (32KB) + wtlo (32KB)
  size_t o_gw    = alloc((size_t)E * 4);             // per-node in-CSR payload (src)
  size_t o_inBL  = alloc((size_t)E * 4);             // in-bucket list {src<<6|dstLocal}
  size_t o_gw2   = alloc((size_t)E * 8);             // out-bucket payload {w, (r&63)<<6|g}
  size_t o_bufA  = alloc((size_t)n * HDIM * 4);      // h2 (gemm out)
  size_t o_bufB  = alloc((size_t)n * HDIM * 4);      // zhi+zlo; partials alias after gemm
  (void)n_in; (void)out_size; (void)ws_size;

  int*    deg      = (int*)(w + o_deg);
  float*  pooled   = (float*)(w + o_pool);
  int*    bcntI    = (int*)(w + o_bcntI);
  int*    bcntO    = (int*)(w + o_bcntO);
  int*    ts       = (int*)(w + o_ts);
  int*    boffI    = (int*)(w + o_boffI);
  int*    curI     = (int*)(w + o_curI);
  int*    boffO    = (int*)(w + o_boffO);
  int*    curO     = (int*)(w + o_curO);
  int2*   od       = (int2*)(w + o_od);
  float2* dx       = (float2*)(w + o_dx);
  float2* sd       = (float2*)(w + o_sd);
  unsigned short* wthi = (unsigned short*)(w + o_wt);
  unsigned short* wtlo = wthi + HDIM * HDIM;
  int*    gwi      = (int*)(w + o_gw);
  int*    inBL     = (int*)(w + o_inBL);
  int2*   gw2      = (int2*)(w + o_gw2);
  float*  bufA     = (float*)(w + o_bufA);
  unsigned short* zhi = (unsigned short*)(w + o_bufB);
  unsigned short* zlo = zhi + (size_t)n * HDIM;
  float*  partials = (float*)(w + o_bufB);           // alias (z dead after gemm)

  hipMemsetAsync(w + o_deg, 0, zero_end - o_deg, stream);

  const int nTiles = (n + 1023) / 1024;
  const int cB = (E + 2047) / 2048;  // 8 contiguous edges per thread
  k_countw<<<cB + 64, 256, 0, stream>>>(colv, rowv, E, deg, bcntI, bcntO, W2,
                                        wthi, wtlo, cB, NB);
  k_scan1<<<nTiles, 256, 0, stream>>>(deg, n, bat, x, od, dx, sd, ts);
  k_scan2<<<1, 128, 0, stream>>>(ts, nTiles);
  k_bscan2<<<1, 1024, 0, stream>>>(bcntI, boffI, curI, bcntO, boffO, curO, NB, E);

  // fused dual-brank + edge processing
  k_edge<<<(E + 4095) / 4096, 256, 0, stream>>>(rowv, colv, E, od, dx, curI, curO,
                                                inBL, gw2, sd, NB);

  // bucket list -> per-node in-CSR
  k_rank2<<<NB, 256, 0, stream>>>(inBL, boffI, od, ts, gwi, n);

  // fused rank-1 h1 + relu + layer-2 aggregation -> z as bf16 hi/lo
  k_l2in<<<(n + 3) / 4, 256, 0, stream>>>(sd, od, ts, gwi, W1, b1,
                                          (ushort2*)zhi, (ushort2*)zlo, n, E);

  // layer 2 GEMM (+bias+relu) on the MFMA pipe: 3-term bf16 split
  k_gemm_mfma<<<(n + 127) / 128, 256, 0, stream>>>(zhi, zlo, wthi, wtlo, b2, bufA, n);

  // layer 3 + pool: P-tile rebuilt in LDS from bucket-CSR; partials then reduced
  k_pgemm<<<nPB, 256, 0, stream>>>(bufA, gw2, boffO, od, partials, n);
  k_reduce<<<dim3(32, 8), 256, 0, stream>>>(partials, pooled, nPB);

  // fused tail: mid GEMM + classifier
  k_mid<<<NGRAPH, HDIM, 0, stream>>>(pooled, bat, n, W3, b3, Wl, bl, out);
}